// Round 14
// baseline (723.051 us; speedup 1.0000x reference)
//
#include <hip/hip_runtime.h>
#include <math.h>

#define NRAY 8192
#define SSAMP 128
#define HD 256
#define AROW 264    // LDS row pitch in bf16
#define A1ROW 40    // layer1 A-tile pitch
#define FIXCAP 262144
#define FIXTHR 0.025f

typedef short s16x8 __attribute__((ext_vector_type(8)));
typedef float f32x4 __attribute__((ext_vector_type(4)));

// ---------- bf16 helpers ----------
__device__ __forceinline__ unsigned short f2bf(float f) {      // RNE
    unsigned u = __float_as_uint(f);
    u += 0x7fffu + ((u >> 16) & 1u);
    return (unsigned short)(u >> 16);
}
__device__ __forceinline__ unsigned short f2bf_t(float f) {    // truncate (1-term tier)
    return (unsigned short)(__float_as_uint(f) >> 16);
}
__device__ __forceinline__ float bf2f(unsigned short s) {
    return __uint_as_float(((unsigned)s) << 16);
}
__device__ __forceinline__ void split2(float f, unsigned short& hi, unsigned short& lo) {
    unsigned u = __float_as_uint(f);
    hi = (unsigned short)(u >> 16);
    float r = f - __uint_as_float(u & 0xFFFF0000u);
    lo = f2bf(r);
}
// exact softplus (fixup / final tier)
__device__ __forceinline__ float softplus_fast(float x) {
    return fmaxf(x, 0.0f) + __logf(1.0f + __expf(-fabsf(x)));
}
// cheap softplus (1-term tier)
__device__ __forceinline__ float softplus_cheap(float x) {
    float m = __expf(-fabsf(x));
    float p = fmaf(m, fmaf(0.14258f, m, -0.44943f), 1.0f);
    return fmaxf(x, 0.0f) + m * p;
}
__device__ __forceinline__ float sigmoid_fast(float x) {
    return 1.0f / (1.0f + __expf(-x));
}

// ---------------- prep: pack W2/W3, pack layer1 B, cube intersection, zero counter ----------------
__global__ __launch_bounds__(256)
void prep_kernel(const float* __restrict__ W1, const float* __restrict__ b1,
                 const float* __restrict__ W2, const float* __restrict__ W3,
                 const float* __restrict__ ray0, const float* __restrict__ rdg,
                 unsigned short* __restrict__ P2, unsigned short* __restrict__ P3,
                 unsigned short* __restrict__ B1, float* __restrict__ rayinfo,
                 int* __restrict__ fix_cnt) {
    const int b = blockIdx.x, tid = threadIdx.x;
    if (b < 256) {
        int idx = b * 256 + tid;   // 0..65535
        int k = idx >> 8, n = idx & 255;
        int nt = n >> 4, kt = k >> 5, lq = (k >> 3) & 3, j = k & 7;
        int lane = (lq << 4) | (n & 15);
        size_t off = (size_t)((nt * 8 + kt) * 2) * 512 + (size_t)lane * 8 + j;
        float w = W2[idx];
        unsigned short hi = f2bf(w);
        P2[off] = hi; P2[off + 512] = f2bf(w - bf2f(hi));
        w = W3[idx];
        hi = f2bf(w);
        P3[off] = hi; P3[off + 512] = f2bf(w - bf2f(hi));
    } else if (b < 288) {
        int idx = (b - 256) * 256 + tid;   // 0..8191
        int w = idx & 511;
        int lane = w >> 3, j = w & 7;
        int k = ((lane >> 4) << 3) + j;
        int n = ((idx >> 9) << 4) + (lane & 15);
        unsigned short s = 0;
        if (k < 3) s = f2bf(W1[k * HD + n]);
        else if (k == 3) s = f2bf(b1[n]);
        else if (k < 7) s = f2bf(W1[(k - 4) * HD + n]);
        else if (k == 7) { unsigned short bh = f2bf(b1[n]); s = f2bf(b1[n] - bf2f(bh)); }
        else if (k < 11) { float wv = W1[(k - 8) * HD + n]; unsigned short wh = f2bf(wv); s = f2bf(wv - bf2f(wh)); }
        B1[idx] = s;
    } else {
        int r = (b - 288) * 256 + tid;     // 0..8191
        if (r == 0) *fix_cnt = 0;
        float o0 = ray0[3 * r], o1 = ray0[3 * r + 1], o2 = ray0[3 * r + 2];
        float v0 = rdg[3 * r], v1 = rdg[3 * r + 1], v2 = rdg[3 * r + 2];
        const float pd = 0.55f, lim = pd + 1e-6f;
        float di[6]; int insk[6]; int cnt = 0;
        for (int k = 0; k < 6; k++) {
            int a = k % 3;
            float pl = (k < 3) ? pd : -pd;
            float den = (a == 0) ? v0 : ((a == 1) ? v1 : v2);
            if (fabsf(den) < 1e-9f) den = 1e-9f;
            float oa = (a == 0) ? o0 : ((a == 1) ? o1 : o2);
            float dd = (pl - oa) / den;
            float px = o0 + dd * v0, py = o1 + dd * v1, pz = o2 + dd * v2;
            int ins = (fabsf(px) <= lim) && (fabsf(py) <= lim) && (fabsf(pz) <= lim);
            di[k] = dd; insk[k] = ins; cnt += ins;
        }
        float d0 = 0.f, sl = 2.4f;
        if (cnt == 2) {
            int k1 = -1, k2 = -1;
            for (int k = 0; k < 6; k++) if (insk[k]) { if (k1 < 0) k1 = k; else k2 = k; }
            float nrd = sqrtf(v0 * v0 + v1 * v1 + v2 * v2);
            float ax = di[k1] * v0, ay = di[k1] * v1, az = di[k1] * v2;
            float d1n = sqrtf(ax * ax + ay * ay + az * az) / nrd;
            float bx = di[k2] * v0, by = di[k2] * v1, bz = di[k2] * v2;
            float d2n = sqrtf(bx * bx + by * by + bz * bz) / nrd;
            d0 = fminf(d1n, d2n);
            sl = fmaxf(d1n, d2n) - d0;
        }
        float* ri = rayinfo + (size_t)r * 8;
        ri[0] = d0; ri[1] = sl;
        ri[2] = o0; ri[3] = o1; ri[4] = o2;
        ri[5] = v0; ri[6] = v1; ri[7] = v2;
    }
}

// ---------- layer1 GEMM (NT=4/wave) ----------
template<int MT>
__device__ __forceinline__ void gemm_l1(const unsigned short* A1,
                                        const unsigned short* __restrict__ B1,
                                        f32x4 acc[MT][4], int lane, int ntbase) {
    const int r15 = lane & 15, q = lane >> 4;
    s16x8 bh[4];
#pragma unroll
    for (int nt = 0; nt < 4; nt++)
        bh[nt] = *(((const s16x8*)B1) + (size_t)(ntbase + nt) * 64 + lane);
#pragma unroll
    for (int mt = 0; mt < MT; mt++) {
        s16x8 ah = *(const s16x8*)(A1 + (mt * 16 + r15) * A1ROW + q * 8);
#pragma unroll
        for (int nt = 0; nt < 4; nt++)
            acc[mt][nt] = __builtin_amdgcn_mfma_f32_16x16x32_bf16(ah, bh[nt], (f32x4){0.f,0.f,0.f,0.f}, 0, 0, 0);
    }
}

// ---------- 1-term bf16 GEMM (NT=4/wave) ----------
template<int MT>
__device__ __forceinline__ void gemm_1t(const unsigned short* Ahi,
                                        const unsigned short* __restrict__ Bp,
                                        f32x4 acc[MT][4], int lane, int ntbase) {
#pragma unroll
    for (int mt = 0; mt < MT; mt++)
#pragma unroll
        for (int nt = 0; nt < 4; nt++) acc[mt][nt] = (f32x4){0.f, 0.f, 0.f, 0.f};
    const int r15 = lane & 15, q = lane >> 4;
#pragma unroll 2
    for (int kt = 0; kt < 8; kt++) {
        s16x8 bh[4];
#pragma unroll
        for (int nt = 0; nt < 4; nt++) {
            const s16x8* bp = ((const s16x8*)Bp) + (size_t)((ntbase + nt) * 8 + kt) * 128 + lane;
            bh[nt] = bp[0];
        }
        const int kc = kt * 32 + q * 8;
#pragma unroll
        for (int mt = 0; mt < MT; mt++) {
            s16x8 ah = *(const s16x8*)(Ahi + (mt * 16 + r15) * AROW + kc);
#pragma unroll
            for (int nt = 0; nt < 4; nt++)
                acc[mt][nt] = __builtin_amdgcn_mfma_f32_16x16x32_bf16(ah, bh[nt], acc[mt][nt], 0, 0, 0);
        }
    }
}

// ---------- 3-term split GEMM (fixup tier, NT=4/wave) ----------
template<int MT>
__device__ __forceinline__ void gemm_3t(const unsigned short* Ahi, const unsigned short* Alo,
                                        const unsigned short* __restrict__ Bp,
                                        f32x4 acc[MT][4], int lane, int ntbase) {
#pragma unroll
    for (int mt = 0; mt < MT; mt++)
#pragma unroll
        for (int nt = 0; nt < 4; nt++) acc[mt][nt] = (f32x4){0.f, 0.f, 0.f, 0.f};
    const int r15 = lane & 15, q = lane >> 4;
#pragma unroll 2
    for (int kt = 0; kt < 8; kt++) {
        s16x8 bh[4], bl[4];
#pragma unroll
        for (int nt = 0; nt < 4; nt++) {
            const s16x8* bp = ((const s16x8*)Bp) + (size_t)((ntbase + nt) * 8 + kt) * 128 + lane;
            bh[nt] = bp[0];
            bl[nt] = bp[64];
        }
        const int kc = kt * 32 + q * 8;
#pragma unroll
        for (int mt = 0; mt < MT; mt++) {
            s16x8 ah = *(const s16x8*)(Ahi + (mt * 16 + r15) * AROW + kc);
            s16x8 al = *(const s16x8*)(Alo + (mt * 16 + r15) * AROW + kc);
#pragma unroll
            for (int nt = 0; nt < 4; nt++) {
                acc[mt][nt] = __builtin_amdgcn_mfma_f32_16x16x32_bf16(ah, bh[nt], acc[mt][nt], 0, 0, 0);
                acc[mt][nt] = __builtin_amdgcn_mfma_f32_16x16x32_bf16(ah, bl[nt], acc[mt][nt], 0, 0, 0);
                acc[mt][nt] = __builtin_amdgcn_mfma_f32_16x16x32_bf16(al, bh[nt], acc[mt][nt], 0, 0, 0);
            }
        }
    }
}

// epilogue (layer1, bias folded): cheap softplus + truncating store (NT=4)
template<int MT>
__device__ __forceinline__ void epi_l1(f32x4 acc[MT][4], unsigned short* Ahi, int lane, int wn0) {
    const int r15 = lane & 15, q = lane >> 4;
#pragma unroll
    for (int mt = 0; mt < MT; mt++)
#pragma unroll
        for (int nt = 0; nt < 4; nt++) {
            int col = wn0 + nt * 16 + r15;
#pragma unroll
            for (int reg = 0; reg < 4; reg++) {
                int row = mt * 16 + q * 4 + reg;
                Ahi[row * AROW + col] = f2bf_t(softplus_cheap(acc[mt][nt][reg]));
            }
        }
}

// epilogue (layer1, bias folded): exact softplus + split (fixup tier, NT=4)
template<int MT>
__device__ __forceinline__ void epi_l1_sp(f32x4 acc[MT][4], unsigned short* Ahi, unsigned short* Alo,
                                          int lane, int wn0) {
    const int r15 = lane & 15, q = lane >> 4;
#pragma unroll
    for (int mt = 0; mt < MT; mt++)
#pragma unroll
        for (int nt = 0; nt < 4; nt++) {
            int col = wn0 + nt * 16 + r15;
#pragma unroll
            for (int reg = 0; reg < 4; reg++) {
                int row = mt * 16 + q * 4 + reg;
                float h = softplus_fast(acc[mt][nt][reg]);
                unsigned short hi, lo;
                split2(h, hi, lo);
                Ahi[row * AROW + col] = hi;
                Alo[row * AROW + col] = lo;
            }
        }
}

// epilogue (1-term, NT=4): cheap softplus + truncating store
template<int MT>
__device__ __forceinline__ void epi_hidden_1t(f32x4 acc[MT][4], const float* __restrict__ b,
                                              unsigned short* Ahi, int lane, int wn0) {
    const int r15 = lane & 15, q = lane >> 4;
#pragma unroll
    for (int mt = 0; mt < MT; mt++)
#pragma unroll
        for (int nt = 0; nt < 4; nt++) {
            int col = wn0 + nt * 16 + r15;
            float bb = b[col];
#pragma unroll
            for (int reg = 0; reg < 4; reg++) {
                int row = mt * 16 + q * 4 + reg;
                Ahi[row * AROW + col] = f2bf_t(softplus_cheap(acc[mt][nt][reg] + bb));
            }
        }
}

// epilogue (split hi/lo, fixup tier, NT=4) — exact softplus
template<int MT>
__device__ __forceinline__ void epi_hidden_sp(f32x4 acc[MT][4], const float* __restrict__ b,
                                              unsigned short* Ahi, unsigned short* Alo,
                                              int lane, int wn0) {
    const int r15 = lane & 15, q = lane >> 4;
#pragma unroll
    for (int mt = 0; mt < MT; mt++)
#pragma unroll
        for (int nt = 0; nt < 4; nt++) {
            int col = wn0 + nt * 16 + r15;
            float bb = b[col];
#pragma unroll
            for (int reg = 0; reg < 4; reg++) {
                int row = mt * 16 + q * 4 + reg;
                float h = softplus_fast(acc[mt][nt][reg] + bb);
                unsigned short hi, lo;
                split2(h, hi, lo);
                Ahi[row * AROW + col] = hi;
                Alo[row * AROW + col] = lo;
            }
        }
}

// layer3 activation + W4 dot (NT=4); CH selects cheap vs exact softplus
template<int MT, bool CH>
__device__ __forceinline__ void l4_reduce(f32x4 acc[MT][4], const float* __restrict__ b3,
                                          const float* __restrict__ W4,
                                          float* partial, int lane, int wn0) {
    const int r15 = lane & 15, q = lane >> 4;
    float w4v[4], b3v[4];
#pragma unroll
    for (int nt = 0; nt < 4; nt++) {
        int col = wn0 + nt * 16 + r15;
        w4v[nt] = W4[col]; b3v[nt] = b3[col];
    }
#pragma unroll
    for (int mt = 0; mt < MT; mt++)
#pragma unroll
        for (int reg = 0; reg < 4; reg++) {
            float p = 0.f;
#pragma unroll
            for (int nt = 0; nt < 4; nt++) {
                float z = acc[mt][nt][reg] + b3v[nt];
                float h = CH ? softplus_cheap(z) : softplus_fast(z);
                p += h * w4v[nt];
            }
#pragma unroll
            for (int m = 1; m < 16; m <<= 1) p += __shfl_xor(p, m, 64);
            if (r15 == 0) partial[mt * 16 + q * 4 + reg] = p;
        }
}

// ======== NT=8 variants (refine: 128-thread blocks, 2 waves, 8 ntiles/wave) ========
__device__ __forceinline__ void gemm_1t8(const unsigned short* Ahi,
                                         const unsigned short* __restrict__ Bp,
                                         f32x4 acc[8], int lane, int ntbase) {
#pragma unroll
    for (int nt = 0; nt < 8; nt++) acc[nt] = (f32x4){0.f, 0.f, 0.f, 0.f};
    const int r15 = lane & 15, q = lane >> 4;
#pragma unroll 2
    for (int kt = 0; kt < 8; kt++) {
        s16x8 bh[8];
#pragma unroll
        for (int nt = 0; nt < 8; nt++)
            bh[nt] = *(((const s16x8*)Bp) + (size_t)((ntbase + nt) * 8 + kt) * 128 + lane);
        const int kc = kt * 32 + q * 8;
        s16x8 ah = *(const s16x8*)(Ahi + r15 * AROW + kc);
#pragma unroll
        for (int nt = 0; nt < 8; nt++)
            acc[nt] = __builtin_amdgcn_mfma_f32_16x16x32_bf16(ah, bh[nt], acc[nt], 0, 0, 0);
    }
}

__device__ __forceinline__ void gemm_dual8(const unsigned short* Avh, const unsigned short* Avl,
                                           const unsigned short* Ath, const unsigned short* Atl,
                                           const unsigned short* __restrict__ Bp,
                                           f32x4 av[8], f32x4 at[8], int lane, int ntbase) {
#pragma unroll
    for (int nt = 0; nt < 8; nt++) {
        av[nt] = (f32x4){0.f, 0.f, 0.f, 0.f};
        at[nt] = (f32x4){0.f, 0.f, 0.f, 0.f};
    }
    const int r15 = lane & 15, q = lane >> 4;
    for (int kt = 0; kt < 8; kt++) {
        const int kc = kt * 32 + q * 8;
        s16x8 avh = *(const s16x8*)(Avh + r15 * AROW + kc);
        s16x8 avl = *(const s16x8*)(Avl + r15 * AROW + kc);
        s16x8 ath = *(const s16x8*)(Ath + r15 * AROW + kc);
        s16x8 atl = *(const s16x8*)(Atl + r15 * AROW + kc);
#pragma unroll
        for (int nt = 0; nt < 8; nt++) {
            const s16x8* bp = ((const s16x8*)Bp) + (size_t)((ntbase + nt) * 8 + kt) * 128 + lane;
            s16x8 bh = bp[0];
            s16x8 bl = bp[64];
            av[nt] = __builtin_amdgcn_mfma_f32_16x16x32_bf16(avh, bh, av[nt], 0, 0, 0);
            av[nt] = __builtin_amdgcn_mfma_f32_16x16x32_bf16(avh, bl, av[nt], 0, 0, 0);
            av[nt] = __builtin_amdgcn_mfma_f32_16x16x32_bf16(avl, bh, av[nt], 0, 0, 0);
            at[nt] = __builtin_amdgcn_mfma_f32_16x16x32_bf16(ath, bh, at[nt], 0, 0, 0);
            at[nt] = __builtin_amdgcn_mfma_f32_16x16x32_bf16(ath, bl, at[nt], 0, 0, 0);
            at[nt] = __builtin_amdgcn_mfma_f32_16x16x32_bf16(atl, bh, at[nt], 0, 0, 0);
        }
    }
}

__device__ __forceinline__ void epi_hidden8(f32x4 acc[8], const float* __restrict__ b,
                                            unsigned short* Ahi, int lane, int wn0) {
    const int r15 = lane & 15, q = lane >> 4;
#pragma unroll
    for (int nt = 0; nt < 8; nt++) {
        int col = wn0 + nt * 16 + r15;
        float bb = b[col];
#pragma unroll
        for (int reg = 0; reg < 4; reg++) {
            int row = q * 4 + reg;
            Ahi[row * AROW + col] = f2bf_t(softplus_cheap(acc[nt][reg] + bb));
        }
    }
}

__device__ __forceinline__ void epi_dual8(f32x4 av[8], f32x4 at[8], const float* __restrict__ b,
                                          unsigned short* Avh, unsigned short* Avl,
                                          unsigned short* Ath, unsigned short* Atl,
                                          int lane, int wn0) {
    const int r15 = lane & 15, q = lane >> 4;
#pragma unroll
    for (int nt = 0; nt < 8; nt++) {
        int col = wn0 + nt * 16 + r15;
        float bb = b[col];
#pragma unroll
        for (int reg = 0; reg < 4; reg++) {
            int row = q * 4 + reg;
            float z = av[nt][reg] + bb;
            float h = softplus_fast(z);
            float ht = sigmoid_fast(z) * at[nt][reg];
            unsigned short hi, lo;
            split2(h, hi, lo);
            Avh[row * AROW + col] = hi;
            Avl[row * AROW + col] = lo;
            split2(ht, hi, lo);
            Ath[row * AROW + col] = hi;
            Atl[row * AROW + col] = lo;
        }
    }
}

template<bool CH>
__device__ __forceinline__ void l4_reduce8(f32x4 acc[8], const float* __restrict__ b3,
                                           const float* __restrict__ W4,
                                           float* partial, int lane, int wn0) {
    const int r15 = lane & 15, q = lane >> 4;
    float w4v[8], b3v[8];
#pragma unroll
    for (int nt = 0; nt < 8; nt++) {
        int col = wn0 + nt * 16 + r15;
        w4v[nt] = W4[col]; b3v[nt] = b3[col];
    }
#pragma unroll
    for (int reg = 0; reg < 4; reg++) {
        float p = 0.f;
#pragma unroll
        for (int nt = 0; nt < 8; nt++) {
            float z = acc[nt][reg] + b3v[nt];
            float h = CH ? softplus_cheap(z) : softplus_fast(z);
            p += h * w4v[nt];
        }
#pragma unroll
        for (int m = 1; m < 16; m <<= 1) p += __shfl_xor(p, m, 64);
        if (r15 == 0) partial[q * 4 + reg] = p;
    }
}

__device__ __forceinline__ void l4_reduce_dual8(f32x4 av[8], f32x4 at[8],
                                                const float* __restrict__ b3, const float* __restrict__ W4,
                                                float* pv, float* pt, int lane, int wn0) {
    const int r15 = lane & 15, q = lane >> 4;
    float w4v[8], b3v[8];
#pragma unroll
    for (int nt = 0; nt < 8; nt++) {
        int col = wn0 + nt * 16 + r15;
        w4v[nt] = W4[col]; b3v[nt] = b3[col];
    }
#pragma unroll
    for (int reg = 0; reg < 4; reg++) {
        float sv = 0.f, st = 0.f;
#pragma unroll
        for (int nt = 0; nt < 8; nt++) {
            float z = av[nt][reg] + b3v[nt];
            sv += softplus_fast(z) * w4v[nt];
            st += sigmoid_fast(z) * at[nt][reg] * w4v[nt];
        }
#pragma unroll
        for (int m = 1; m < 16; m <<= 1) {
            sv += __shfl_xor(sv, m, 64);
            st += __shfl_xor(st, m, 64);
        }
        if (r15 == 0) {
            pv[q * 4 + reg] = sv;
            pt[q * 4 + reg] = st;
        }
    }
}

// ---------------- coarse: block = (ray, half), 64 samples, MFMA layer1, inline flag ----------------
__global__ __launch_bounds__(256, 4)
void coarse_mfma(const float* __restrict__ rayinfo,
                 const unsigned short* __restrict__ B1,
                 const unsigned short* __restrict__ P2, const float* __restrict__ b2,
                 const unsigned short* __restrict__ P3, const float* __restrict__ b3,
                 const float* __restrict__ W4, const float* __restrict__ b4,
                 float* __restrict__ val_out, float* __restrict__ dprop_out,
                 int* __restrict__ fix_cnt, int* __restrict__ fix_list) {
    __shared__ __align__(16) unsigned short Ahi[64 * AROW];
    __shared__ __align__(16) unsigned short A1[64 * A1ROW];
    float* partial = (float*)A1;
    const int tid = threadIdx.x;
    const int lane = tid & 63, wave = tid >> 6;
    const int r = blockIdx.x >> 1, half = blockIdx.x & 1;

    if (tid < 64) {
        const float* ri = rayinfo + (size_t)r * 8;
        const int s = half * 64 + tid;
        float t = (float)s * (1.0f / 127.0f);
        float d = fmaf(t, ri[1], ri[0]);
        dprop_out[r * SSAMP + s] = d;
        float px = fmaf(d, ri[5], ri[2]);
        float py = fmaf(d, ri[6], ri[3]);
        float pz = fmaf(d, ri[7], ri[4]);
        unsigned short hx, lx, hy, ly, hz, lz;
        split2(px, hx, lx); split2(py, hy, ly); split2(pz, hz, lz);
        unsigned short* row = A1 + tid * A1ROW;
        row[0] = hx; row[1] = hy; row[2] = hz; row[3] = 0x3F80u;
        row[4] = lx; row[5] = ly; row[6] = lz; row[7] = 0x3F80u;
        row[8] = hx; row[9] = hy; row[10] = hz;
#pragma unroll
        for (int c = 11; c < 32; c++) row[c] = 0;
    }
    __syncthreads();
    f32x4 acc[4][4];
    gemm_l1<4>(A1, B1, acc, lane, wave * 4);
    epi_l1<4>(acc, Ahi, lane, wave * 64);
    __syncthreads();
    gemm_1t<4>(Ahi, P2, acc, lane, wave * 4);
    __syncthreads();
    epi_hidden_1t<4>(acc, b2, Ahi, lane, wave * 64);
    __syncthreads();
    gemm_1t<4>(Ahi, P3, acc, lane, wave * 4);
    l4_reduce<4, true>(acc, b3, W4, &partial[wave * 64], lane, wave * 64);
    __syncthreads();
    if (tid < 64) {
        float v = partial[tid] + partial[64 + tid] + partial[128 + tid] + partial[192 + tid] + b4[0];
        int idx = r * SSAMP + half * 64 + tid;
        val_out[idx] = v;
        if (fabsf(v) < FIXTHR) {
            int pos = atomicAdd(fix_cnt, 1);
            if (pos < FIXCAP) fix_list[pos] = idx;
        }
    }
}

// ---------------- fixup (64-sample 3-term MFMA batches, MFMA layer1) ----------------
__global__ __launch_bounds__(256, 2)
void fixup3_mfma(const int* __restrict__ counter, const int* __restrict__ list,
                 float* __restrict__ val, const float* __restrict__ dprop,
                 const float* __restrict__ ray0, const float* __restrict__ rdg,
                 const unsigned short* __restrict__ B1,
                 const unsigned short* __restrict__ P2, const float* __restrict__ b2,
                 const unsigned short* __restrict__ P3, const float* __restrict__ b3,
                 const float* __restrict__ W4, const float* __restrict__ b4) {
    __shared__ __align__(16) unsigned short Ahi[64 * AROW];
    __shared__ __align__(16) unsigned short Alo[64 * AROW];
    __shared__ __align__(16) unsigned short A1[64 * A1ROW];
    __shared__ float partial[4][64];
    __shared__ int bidxs[64];
    const int cnt = min(*counter, FIXCAP);
    const int base = blockIdx.x * 64;
    if (base >= cnt) return;
    const int tid = threadIdx.x;
    const int lane = tid & 63, wave = tid >> 6;
    if (tid < 64) {
        const int i = min(base + tid, cnt - 1);
        const int bidx = list[i];
        bidxs[tid] = bidx;
        const int rr = bidx >> 7;
        float d = dprop[bidx];
        float px = ray0[3 * rr] + d * rdg[3 * rr];
        float py = ray0[3 * rr + 1] + d * rdg[3 * rr + 1];
        float pz = ray0[3 * rr + 2] + d * rdg[3 * rr + 2];
        unsigned short hx, lx, hy, ly, hz, lz;
        split2(px, hx, lx); split2(py, hy, ly); split2(pz, hz, lz);
        unsigned short* row = A1 + tid * A1ROW;
        row[0] = hx; row[1] = hy; row[2] = hz; row[3] = 0x3F80u;
        row[4] = lx; row[5] = ly; row[6] = lz; row[7] = 0x3F80u;
        row[8] = hx; row[9] = hy; row[10] = hz;
#pragma unroll
        for (int c = 11; c < 32; c++) row[c] = 0;
    }
    __syncthreads();
    f32x4 acc[4][4];
    gemm_l1<4>(A1, B1, acc, lane, wave * 4);
    epi_l1_sp<4>(acc, Ahi, Alo, lane, wave * 64);
    __syncthreads();
    gemm_3t<4>(Ahi, Alo, P2, acc, lane, wave * 4);
    __syncthreads();
    epi_hidden_sp<4>(acc, b2, Ahi, Alo, lane, wave * 64);
    __syncthreads();
    gemm_3t<4>(Ahi, Alo, P3, acc, lane, wave * 4);
    l4_reduce<4, false>(acc, b3, W4, &partial[wave][0], lane, wave * 64);
    __syncthreads();
    if (tid < 64) {
        float v = partial[0][tid] + partial[1][tid] + partial[2][tid] + partial[3][tid] + b4[0];
        val[bidxs[tid]] = v;
    }
}

// ---------------- refine: scan + 8-iter secant + final dual (8 rays / 128-thread block) ----------------
// 1024 blocks, 2 waves each, 8 ntiles/wave; 4 blocks/CU (LDS ~34 KB) for latency hiding.
__global__ __launch_bounds__(128, 2)
void refine_mfma(const float* __restrict__ val, const float* __restrict__ dprop,
                 const float* __restrict__ ray0, const float* __restrict__ rdg,
                 const float* __restrict__ W1, const float* __restrict__ b1,
                 const unsigned short* __restrict__ P2, const float* __restrict__ b2,
                 const unsigned short* __restrict__ P3, const float* __restrict__ b3,
                 const float* __restrict__ W4, const float* __restrict__ b4,
                 float* __restrict__ out) {
    __shared__ __align__(16) unsigned short Avh[16 * AROW];
    __shared__ __align__(16) unsigned short Avl[16 * AROW];
    __shared__ __align__(16) unsigned short Ath[16 * AROW];
    __shared__ __align__(16) unsigned short Atl[16 * AROW];
    __shared__ float partial[2][16], ptan[2][16];
    __shared__ float dl[8], fl[8], dh[8], fh[8], dps[8];
    __shared__ int mks[8];
    unsigned short* Ahi = Avh;   // secant reuses plane 0
    const int tid = threadIdx.x;
    const int lane = tid & 63, wave = tid >> 6;   // wave 0..1
    const int r0 = blockIdx.x * 8;

    // ---- scan: wave w handles rays r0 + w*4 + i ----
    for (int i = 0; i < 4; i++) {
        const int r = r0 + wave * 4 + i;
        const float2 v = *(const float2*)(val + (size_t)r * SSAMP + lane * 2);
        const float2 dd = *(const float2*)(dprop + (size_t)r * SSAMP + lane * 2);
        float vnext = __shfl_down(v.x, 1, 64);
        const int s0 = lane * 2, s1 = s0 + 1;
        float pr0 = v.x * v.y;
        int sg0 = (pr0 > 0.f) ? 1 : ((pr0 < 0.f) ? -1 : 0);
        int k0 = (sg0 * (SSAMP - s0) + 129) * 256 + s0;
        int k1;
        if (lane == 63) {
            k1 = (1 + 129) * 256 + 127;
        } else {
            float pr1 = v.y * vnext;
            int sg1 = (pr1 > 0.f) ? 1 : ((pr1 < 0.f) ? -1 : 0);
            k1 = (sg1 * (SSAMP - s1) + 129) * 256 + s1;
        }
        int k = min(k0, k1);
#pragma unroll
        for (int m = 1; m < 64; m <<= 1) k = min(k, __shfl_xor(k, m, 64));
        int bidx = k & 255;
        int cmin = (k >> 8) - 129;
        int idxh = min(bidx + 1, SSAMP - 1);
        int ow = bidx >> 1, oh = idxh >> 1;
        float fa = __shfl(v.x, ow, 64), fb = __shfl(v.y, ow, 64);
        float da = __shfl(dd.x, ow, 64), db = __shfl(dd.y, ow, 64);
        float fa2 = __shfl(v.x, oh, 64), fb2 = __shfl(v.y, oh, 64);
        float da2 = __shfl(dd.x, oh, 64), db2 = __shfl(dd.y, oh, 64);
        float v0 = __shfl(v.x, 0, 64);
        if (lane == 0) {
            float f_low = (bidx & 1) ? fb : fa;
            float d_low = (bidx & 1) ? db : da;
            float f_high = (idxh & 1) ? fb2 : fa2;
            float d_high = (idxh & 1) ? db2 : da2;
            int sl = wave * 4 + i;
            mks[sl] = (cmin < 0) && (f_low < 0.f) && (v0 < 0.f);
            float den = f_high - f_low;
            if (fabsf(den) < 1e-12f) den = 1e-12f;
            dl[sl] = d_low; fl[sl] = f_low; dh[sl] = d_high; fh[sl] = f_high;
            dps[sl] = -f_low * (d_high - d_low) / den + d_low;
        }
    }
    __syncthreads();
    // ---- 8 secant iterations (1-term, cheap softplus) ----
    for (int it = 0; it < 8; it++) {
        {
            const int pt = tid >> 4, jb = (tid & 15) << 4;   // pt 0..7 = ray
            const int rr = r0 + pt;
            float d = dps[pt];
            float px = ray0[3 * rr] + d * rdg[3 * rr];
            float py = ray0[3 * rr + 1] + d * rdg[3 * rr + 1];
            float pz = ray0[3 * rr + 2] + d * rdg[3 * rr + 2];
            for (int j = jb; j < jb + 16; j += 4) {
                float4 wa = *(const float4*)(W1 + j);
                float4 wb = *(const float4*)(W1 + 256 + j);
                float4 wc = *(const float4*)(W1 + 512 + j);
                float4 bb = *(const float4*)(b1 + j);
                float z[4];
                z[0] = fmaf(px, wa.x, fmaf(py, wb.x, fmaf(pz, wc.x, bb.x)));
                z[1] = fmaf(px, wa.y, fmaf(py, wb.y, fmaf(pz, wc.y, bb.y)));
                z[2] = fmaf(px, wa.z, fmaf(py, wb.z, fmaf(pz, wc.z, bb.z)));
                z[3] = fmaf(px, wa.w, fmaf(py, wb.w, fmaf(pz, wc.w, bb.w)));
#pragma unroll
                for (int i = 0; i < 4; i++)
                    Ahi[pt * AROW + j + i] = f2bf_t(softplus_cheap(z[i]));
            }
        }
        __syncthreads();
        f32x4 acc[8];
        gemm_1t8(Ahi, P2, acc, lane, wave * 8);
        __syncthreads();
        epi_hidden8(acc, b2, Ahi, lane, wave * 128);
        __syncthreads();
        gemm_1t8(Ahi, P3, acc, lane, wave * 8);
        l4_reduce8<true>(acc, b3, W4, &partial[wave][0], lane, wave * 128);
        __syncthreads();
        if (tid < 8) {
            float fm = partial[0][tid] + partial[1][tid] + b4[0];
            float dpv = dps[tid];
            float dlv = dl[tid], flv = fl[tid], dhv = dh[tid], fhv = fh[tid];
            if (fm < 0.f) { dlv = dpv; flv = fm; } else { dhv = dpv; fhv = fm; }
            float den = fhv - flv;
            if (fabsf(den) < 1e-12f) den = 1e-12f;
            dps[tid] = -flv * (dhv - dlv) / den + dlv;
            dl[tid] = dlv; fl[tid] = flv; dh[tid] = dhv; fh[tid] = fhv;
        }
        __syncthreads();
    }
    // ---- final: dual-number 3-term eval + implicit correction ----
    {
        const int pt = tid >> 4, jb = (tid & 15) << 4;
        const int rr = r0 + pt;
        float d = dps[pt];
        float v0 = rdg[3 * rr], v1 = rdg[3 * rr + 1], v2 = rdg[3 * rr + 2];
        float px = ray0[3 * rr] + d * v0;
        float py = ray0[3 * rr + 1] + d * v1;
        float pz = ray0[3 * rr + 2] + d * v2;
        for (int j = jb; j < jb + 16; j += 4) {
            float4 wa = *(const float4*)(W1 + j);
            float4 wb = *(const float4*)(W1 + 256 + j);
            float4 wc = *(const float4*)(W1 + 512 + j);
            float4 bb = *(const float4*)(b1 + j);
            float z[4], zt[4];
            z[0] = fmaf(px, wa.x, fmaf(py, wb.x, fmaf(pz, wc.x, bb.x)));
            z[1] = fmaf(px, wa.y, fmaf(py, wb.y, fmaf(pz, wc.y, bb.y)));
            z[2] = fmaf(px, wa.z, fmaf(py, wb.z, fmaf(pz, wc.z, bb.z)));
            z[3] = fmaf(px, wa.w, fmaf(py, wb.w, fmaf(pz, wc.w, bb.w)));
            zt[0] = fmaf(v0, wa.x, fmaf(v1, wb.x, v2 * wc.x));
            zt[1] = fmaf(v0, wa.y, fmaf(v1, wb.y, v2 * wc.y));
            zt[2] = fmaf(v0, wa.z, fmaf(v1, wb.z, v2 * wc.z));
            zt[3] = fmaf(v0, wa.w, fmaf(v1, wb.w, v2 * wc.w));
#pragma unroll
            for (int i = 0; i < 4; i++) {
                float h = softplus_fast(z[i]);
                float ht = sigmoid_fast(z[i]) * zt[i];
                unsigned short hi, lo;
                split2(h, hi, lo);
                Avh[pt * AROW + j + i] = hi;
                Avl[pt * AROW + j + i] = lo;
                split2(ht, hi, lo);
                Ath[pt * AROW + j + i] = hi;
                Atl[pt * AROW + j + i] = lo;
            }
        }
        // zero pad rows once (rows 8..15) so poison bytes can't make NaNs (row-isolated anyway)
        if (tid < 128) {
            for (int row = 8 + (tid >> 4); row < 16; row += 8) {
                for (int j = jb; j < jb + 16; j++) {
                    Avh[row * AROW + j] = 0; Avl[row * AROW + j] = 0;
                    Ath[row * AROW + j] = 0; Atl[row * AROW + j] = 0;
                }
            }
        }
    }
    __syncthreads();
    f32x4 av[8], at[8];
    gemm_dual8(Avh, Avl, Ath, Atl, P2, av, at, lane, wave * 8);
    __syncthreads();
    epi_dual8(av, at, b2, Avh, Avl, Ath, Atl, lane, wave * 128);
    __syncthreads();
    gemm_dual8(Avh, Avl, Ath, Atl, P3, av, at, lane, wave * 8);
    l4_reduce_dual8(av, at, b3, W4, &partial[wave][0], &ptan[wave][0], lane, wave * 128);
    __syncthreads();
    if (tid < 8) {
        float f = partial[0][tid] + partial[1][tid] + b4[0];
        float ft = ptan[0][tid] + ptan[1][tid];
        if (fabsf(ft) < 1e-6f) ft = (ft < 0.f) ? -1e-6f : 1e-6f;
        float dres = dps[tid] - f / ft;
        out[r0 + tid] = mks[tid] ? dres : 0.0f;
    }
}

extern "C" void kernel_launch(void* const* d_in, const int* in_sizes, int n_in,
                              void* d_out, int out_size, void* d_ws, size_t ws_size,
                              hipStream_t stream) {
    const float* ray0 = (const float*)d_in[0];
    const float* rdg  = (const float*)d_in[1];
    const float* W1 = (const float*)d_in[2];
    const float* b1 = (const float*)d_in[3];
    const float* W2 = (const float*)d_in[4];
    const float* b2 = (const float*)d_in[5];
    const float* W3 = (const float*)d_in[6];
    const float* b3 = (const float*)d_in[7];
    const float* W4 = (const float*)d_in[8];
    const float* b4 = (const float*)d_in[9];
    float* out = (float*)d_out;

    float* ws = (float*)d_ws;
    float* val    = ws;                                 // SSAMP*NRAY, r-major [r][s]
    float* dprop  = ws + (size_t)SSAMP * NRAY;          // r-major [r][s]
    unsigned short* P2 = (unsigned short*)(ws + (size_t)2 * SSAMP * NRAY);
    unsigned short* P3 = P2 + 131072;
    unsigned short* B1 = P3 + 131072;       // 8192 shorts
    float* rayinfo = (float*)(B1 + 8192);   // NRAY*8 floats
    int* fix_cnt  = (int*)(rayinfo + (size_t)NRAY * 8);
    int* fix_list = fix_cnt + 64;           // FIXCAP ints

    hipLaunchKernelGGL(prep_kernel, dim3(320), dim3(256), 0, stream,
                       W1, b1, W2, W3, ray0, rdg, P2, P3, B1, rayinfo, fix_cnt);
    hipLaunchKernelGGL(coarse_mfma, dim3(NRAY * 2), dim3(256), 0, stream,
                       rayinfo, B1, P2, b2, P3, b3, W4, b4, val, dprop, fix_cnt, fix_list);
    hipLaunchKernelGGL(fixup3_mfma, dim3(FIXCAP / 64), dim3(256), 0, stream,
                       fix_cnt, fix_list, val, dprop, ray0, rdg,
                       B1, P2, b2, P3, b3, W4, b4);
    hipLaunchKernelGGL(refine_mfma, dim3(NRAY / 8), dim3(128), 0, stream,
                       val, dprop, ray0, rdg, W1, b1, P2, b2, P3, b3, W4, b4, out);
}

// Round 15
// 712.508 us; speedup vs baseline: 1.0148x; 1.0148x over previous
//
#include <hip/hip_runtime.h>
#include <math.h>

#define NRAY 8192
#define SSAMP 128
#define HD 256
#define AROW 264    // LDS row pitch in bf16
#define A1ROW 40    // layer1 A-tile pitch
#define FIXCAP 262144
#define FIXTHR 0.018f   // RNE 1-term tier: error margin ~= trunc tier @ 0.025

typedef short s16x8 __attribute__((ext_vector_type(8)));
typedef float f32x4 __attribute__((ext_vector_type(4)));

// ---------- bf16 helpers ----------
__device__ __forceinline__ unsigned short f2bf(float f) {      // RNE
    unsigned u = __float_as_uint(f);
    u += 0x7fffu + ((u >> 16) & 1u);
    return (unsigned short)(u >> 16);
}
__device__ __forceinline__ float bf2f(unsigned short s) {
    return __uint_as_float(((unsigned)s) << 16);
}
__device__ __forceinline__ void split2(float f, unsigned short& hi, unsigned short& lo) {
    unsigned u = __float_as_uint(f);
    hi = (unsigned short)(u >> 16);
    float r = f - __uint_as_float(u & 0xFFFF0000u);
    lo = f2bf(r);
}
// exact softplus (fixup / final tier)
__device__ __forceinline__ float softplus_fast(float x) {
    return fmaxf(x, 0.0f) + __logf(1.0f + __expf(-fabsf(x)));
}
// cheap softplus (1-term tier)
__device__ __forceinline__ float softplus_cheap(float x) {
    float m = __expf(-fabsf(x));
    float p = fmaf(m, fmaf(0.14258f, m, -0.44943f), 1.0f);
    return fmaxf(x, 0.0f) + m * p;
}
__device__ __forceinline__ float sigmoid_fast(float x) {
    return 1.0f / (1.0f + __expf(-x));
}

// ---------------- prep: pack W2/W3, pack layer1 B, cube intersection, zero counter ----------------
__global__ __launch_bounds__(256)
void prep_kernel(const float* __restrict__ W1, const float* __restrict__ b1,
                 const float* __restrict__ W2, const float* __restrict__ W3,
                 const float* __restrict__ ray0, const float* __restrict__ rdg,
                 unsigned short* __restrict__ P2, unsigned short* __restrict__ P3,
                 unsigned short* __restrict__ B1, float* __restrict__ rayinfo,
                 int* __restrict__ fix_cnt) {
    const int b = blockIdx.x, tid = threadIdx.x;
    if (b < 256) {
        int idx = b * 256 + tid;   // 0..65535
        int k = idx >> 8, n = idx & 255;
        int nt = n >> 4, kt = k >> 5, lq = (k >> 3) & 3, j = k & 7;
        int lane = (lq << 4) | (n & 15);
        size_t off = (size_t)((nt * 8 + kt) * 2) * 512 + (size_t)lane * 8 + j;
        float w = W2[idx];
        unsigned short hi = f2bf(w);
        P2[off] = hi; P2[off + 512] = f2bf(w - bf2f(hi));
        w = W3[idx];
        hi = f2bf(w);
        P3[off] = hi; P3[off + 512] = f2bf(w - bf2f(hi));
    } else if (b < 288) {
        int idx = (b - 256) * 256 + tid;   // 0..8191
        int w = idx & 511;
        int lane = w >> 3, j = w & 7;
        int k = ((lane >> 4) << 3) + j;
        int n = ((idx >> 9) << 4) + (lane & 15);
        unsigned short s = 0;
        if (k < 3) s = f2bf(W1[k * HD + n]);
        else if (k == 3) s = f2bf(b1[n]);
        else if (k < 7) s = f2bf(W1[(k - 4) * HD + n]);
        else if (k == 7) { unsigned short bh = f2bf(b1[n]); s = f2bf(b1[n] - bf2f(bh)); }
        else if (k < 11) { float wv = W1[(k - 8) * HD + n]; unsigned short wh = f2bf(wv); s = f2bf(wv - bf2f(wh)); }
        B1[idx] = s;
    } else {
        int r = (b - 288) * 256 + tid;     // 0..8191
        if (r == 0) *fix_cnt = 0;
        float o0 = ray0[3 * r], o1 = ray0[3 * r + 1], o2 = ray0[3 * r + 2];
        float v0 = rdg[3 * r], v1 = rdg[3 * r + 1], v2 = rdg[3 * r + 2];
        const float pd = 0.55f, lim = pd + 1e-6f;
        float di[6]; int insk[6]; int cnt = 0;
        for (int k = 0; k < 6; k++) {
            int a = k % 3;
            float pl = (k < 3) ? pd : -pd;
            float den = (a == 0) ? v0 : ((a == 1) ? v1 : v2);
            if (fabsf(den) < 1e-9f) den = 1e-9f;
            float oa = (a == 0) ? o0 : ((a == 1) ? o1 : o2);
            float dd = (pl - oa) / den;
            float px = o0 + dd * v0, py = o1 + dd * v1, pz = o2 + dd * v2;
            int ins = (fabsf(px) <= lim) && (fabsf(py) <= lim) && (fabsf(pz) <= lim);
            di[k] = dd; insk[k] = ins; cnt += ins;
        }
        float d0 = 0.f, sl = 2.4f;
        if (cnt == 2) {
            int k1 = -1, k2 = -1;
            for (int k = 0; k < 6; k++) if (insk[k]) { if (k1 < 0) k1 = k; else k2 = k; }
            float nrd = sqrtf(v0 * v0 + v1 * v1 + v2 * v2);
            float ax = di[k1] * v0, ay = di[k1] * v1, az = di[k1] * v2;
            float d1n = sqrtf(ax * ax + ay * ay + az * az) / nrd;
            float bx = di[k2] * v0, by = di[k2] * v1, bz = di[k2] * v2;
            float d2n = sqrtf(bx * bx + by * by + bz * bz) / nrd;
            d0 = fminf(d1n, d2n);
            sl = fmaxf(d1n, d2n) - d0;
        }
        float* ri = rayinfo + (size_t)r * 8;
        ri[0] = d0; ri[1] = sl;
        ri[2] = o0; ri[3] = o1; ri[4] = o2;
        ri[5] = v0; ri[6] = v1; ri[7] = v2;
    }
}

// ---------- layer1 GEMM: one K=32 tile, acc = A1 @ B1 (bias folded in) ----------
template<int MT>
__device__ __forceinline__ void gemm_l1(const unsigned short* A1,
                                        const unsigned short* __restrict__ B1,
                                        f32x4 acc[MT][4], int lane, int ntbase) {
    const int r15 = lane & 15, q = lane >> 4;
    s16x8 bh[4];
#pragma unroll
    for (int nt = 0; nt < 4; nt++)
        bh[nt] = *(((const s16x8*)B1) + (size_t)(ntbase + nt) * 64 + lane);
#pragma unroll
    for (int mt = 0; mt < MT; mt++) {
        s16x8 ah = *(const s16x8*)(A1 + (mt * 16 + r15) * A1ROW + q * 8);
#pragma unroll
        for (int nt = 0; nt < 4; nt++)
            acc[mt][nt] = __builtin_amdgcn_mfma_f32_16x16x32_bf16(ah, bh[nt], (f32x4){0.f,0.f,0.f,0.f}, 0, 0, 0);
    }
}

// ---------- 1-term bf16 GEMM: acc += Ah*Bh ----------
template<int MT>
__device__ __forceinline__ void gemm_1t(const unsigned short* Ahi,
                                        const unsigned short* __restrict__ Bp,
                                        f32x4 acc[MT][4], int lane, int ntbase) {
#pragma unroll
    for (int mt = 0; mt < MT; mt++)
#pragma unroll
        for (int nt = 0; nt < 4; nt++) acc[mt][nt] = (f32x4){0.f, 0.f, 0.f, 0.f};
    const int r15 = lane & 15, q = lane >> 4;
#pragma unroll 2
    for (int kt = 0; kt < 8; kt++) {
        s16x8 bh[4];
#pragma unroll
        for (int nt = 0; nt < 4; nt++) {
            const s16x8* bp = ((const s16x8*)Bp) + (size_t)((ntbase + nt) * 8 + kt) * 128 + lane;
            bh[nt] = bp[0];
        }
        const int kc = kt * 32 + q * 8;
#pragma unroll
        for (int mt = 0; mt < MT; mt++) {
            s16x8 ah = *(const s16x8*)(Ahi + (mt * 16 + r15) * AROW + kc);
#pragma unroll
            for (int nt = 0; nt < 4; nt++)
                acc[mt][nt] = __builtin_amdgcn_mfma_f32_16x16x32_bf16(ah, bh[nt], acc[mt][nt], 0, 0, 0);
        }
    }
}

// ---------- 3-term split GEMM (fixup tier) ----------
template<int MT>
__device__ __forceinline__ void gemm_3t(const unsigned short* Ahi, const unsigned short* Alo,
                                        const unsigned short* __restrict__ Bp,
                                        f32x4 acc[MT][4], int lane, int ntbase) {
#pragma unroll
    for (int mt = 0; mt < MT; mt++)
#pragma unroll
        for (int nt = 0; nt < 4; nt++) acc[mt][nt] = (f32x4){0.f, 0.f, 0.f, 0.f};
    const int r15 = lane & 15, q = lane >> 4;
#pragma unroll 2
    for (int kt = 0; kt < 8; kt++) {
        s16x8 bh[4], bl[4];
#pragma unroll
        for (int nt = 0; nt < 4; nt++) {
            const s16x8* bp = ((const s16x8*)Bp) + (size_t)((ntbase + nt) * 8 + kt) * 128 + lane;
            bh[nt] = bp[0];
            bl[nt] = bp[64];
        }
        const int kc = kt * 32 + q * 8;
#pragma unroll
        for (int mt = 0; mt < MT; mt++) {
            s16x8 ah = *(const s16x8*)(Ahi + (mt * 16 + r15) * AROW + kc);
            s16x8 al = *(const s16x8*)(Alo + (mt * 16 + r15) * AROW + kc);
#pragma unroll
            for (int nt = 0; nt < 4; nt++) {
                acc[mt][nt] = __builtin_amdgcn_mfma_f32_16x16x32_bf16(ah, bh[nt], acc[mt][nt], 0, 0, 0);
                acc[mt][nt] = __builtin_amdgcn_mfma_f32_16x16x32_bf16(ah, bl[nt], acc[mt][nt], 0, 0, 0);
                acc[mt][nt] = __builtin_amdgcn_mfma_f32_16x16x32_bf16(al, bh[nt], acc[mt][nt], 0, 0, 0);
            }
        }
    }
}

// dual (value + tangent) 3-term variant — final tier
template<int MT>
__device__ __forceinline__ void gemm_dual(const unsigned short* Avh, const unsigned short* Avl,
                                          const unsigned short* Ath, const unsigned short* Atl,
                                          const unsigned short* __restrict__ Bp,
                                          f32x4 av[MT][4], f32x4 at[MT][4], int lane, int ntbase) {
#pragma unroll
    for (int mt = 0; mt < MT; mt++)
#pragma unroll
        for (int nt = 0; nt < 4; nt++) {
            av[mt][nt] = (f32x4){0.f, 0.f, 0.f, 0.f};
            at[mt][nt] = (f32x4){0.f, 0.f, 0.f, 0.f};
        }
    const int r15 = lane & 15, q = lane >> 4;
#pragma unroll 2
    for (int kt = 0; kt < 8; kt++) {
        s16x8 bh[4], bl[4];
#pragma unroll
        for (int nt = 0; nt < 4; nt++) {
            const s16x8* bp = ((const s16x8*)Bp) + (size_t)((ntbase + nt) * 8 + kt) * 128 + lane;
            bh[nt] = bp[0];
            bl[nt] = bp[64];
        }
        const int kc = kt * 32 + q * 8;
#pragma unroll
        for (int mt = 0; mt < MT; mt++) {
            s16x8 avh = *(const s16x8*)(Avh + (mt * 16 + r15) * AROW + kc);
            s16x8 avl = *(const s16x8*)(Avl + (mt * 16 + r15) * AROW + kc);
            s16x8 ath = *(const s16x8*)(Ath + (mt * 16 + r15) * AROW + kc);
            s16x8 atl = *(const s16x8*)(Atl + (mt * 16 + r15) * AROW + kc);
#pragma unroll
            for (int nt = 0; nt < 4; nt++) {
                av[mt][nt] = __builtin_amdgcn_mfma_f32_16x16x32_bf16(avh, bh[nt], av[mt][nt], 0, 0, 0);
                av[mt][nt] = __builtin_amdgcn_mfma_f32_16x16x32_bf16(avh, bl[nt], av[mt][nt], 0, 0, 0);
                av[mt][nt] = __builtin_amdgcn_mfma_f32_16x16x32_bf16(avl, bh[nt], av[mt][nt], 0, 0, 0);
                at[mt][nt] = __builtin_amdgcn_mfma_f32_16x16x32_bf16(ath, bh[nt], at[mt][nt], 0, 0, 0);
                at[mt][nt] = __builtin_amdgcn_mfma_f32_16x16x32_bf16(ath, bl[nt], at[mt][nt], 0, 0, 0);
                at[mt][nt] = __builtin_amdgcn_mfma_f32_16x16x32_bf16(atl, bh[nt], at[mt][nt], 0, 0, 0);
            }
        }
    }
}

// epilogue (layer1, bias folded): cheap softplus + RNE store
template<int MT>
__device__ __forceinline__ void epi_l1(f32x4 acc[MT][4], unsigned short* Ahi, int lane, int wn0) {
    const int r15 = lane & 15, q = lane >> 4;
#pragma unroll
    for (int mt = 0; mt < MT; mt++)
#pragma unroll
        for (int nt = 0; nt < 4; nt++) {
            int col = wn0 + nt * 16 + r15;
#pragma unroll
            for (int reg = 0; reg < 4; reg++) {
                int row = mt * 16 + q * 4 + reg;
                Ahi[row * AROW + col] = f2bf(softplus_cheap(acc[mt][nt][reg]));
            }
        }
}

// epilogue (layer1, bias folded): exact softplus + split (fixup tier)
template<int MT>
__device__ __forceinline__ void epi_l1_sp(f32x4 acc[MT][4], unsigned short* Ahi, unsigned short* Alo,
                                          int lane, int wn0) {
    const int r15 = lane & 15, q = lane >> 4;
#pragma unroll
    for (int mt = 0; mt < MT; mt++)
#pragma unroll
        for (int nt = 0; nt < 4; nt++) {
            int col = wn0 + nt * 16 + r15;
#pragma unroll
            for (int reg = 0; reg < 4; reg++) {
                int row = mt * 16 + q * 4 + reg;
                float h = softplus_fast(acc[mt][nt][reg]);
                unsigned short hi, lo;
                split2(h, hi, lo);
                Ahi[row * AROW + col] = hi;
                Alo[row * AROW + col] = lo;
            }
        }
}

// epilogue (1-term): cheap softplus + RNE store
template<int MT>
__device__ __forceinline__ void epi_hidden_1t(f32x4 acc[MT][4], const float* __restrict__ b,
                                              unsigned short* Ahi, int lane, int wn0) {
    const int r15 = lane & 15, q = lane >> 4;
#pragma unroll
    for (int mt = 0; mt < MT; mt++)
#pragma unroll
        for (int nt = 0; nt < 4; nt++) {
            int col = wn0 + nt * 16 + r15;
            float bb = b[col];
#pragma unroll
            for (int reg = 0; reg < 4; reg++) {
                int row = mt * 16 + q * 4 + reg;
                Ahi[row * AROW + col] = f2bf(softplus_cheap(acc[mt][nt][reg] + bb));
            }
        }
}

// epilogue (split hi/lo, fixup tier) — exact softplus
template<int MT>
__device__ __forceinline__ void epi_hidden_sp(f32x4 acc[MT][4], const float* __restrict__ b,
                                              unsigned short* Ahi, unsigned short* Alo,
                                              int lane, int wn0) {
    const int r15 = lane & 15, q = lane >> 4;
#pragma unroll
    for (int mt = 0; mt < MT; mt++)
#pragma unroll
        for (int nt = 0; nt < 4; nt++) {
            int col = wn0 + nt * 16 + r15;
            float bb = b[col];
#pragma unroll
            for (int reg = 0; reg < 4; reg++) {
                int row = mt * 16 + q * 4 + reg;
                float h = softplus_fast(acc[mt][nt][reg] + bb);
                unsigned short hi, lo;
                split2(h, hi, lo);
                Ahi[row * AROW + col] = hi;
                Alo[row * AROW + col] = lo;
            }
        }
}

template<int MT>
__device__ __forceinline__ void epi_dual(f32x4 av[MT][4], f32x4 at[MT][4], const float* __restrict__ b,
                                         unsigned short* Avh, unsigned short* Avl,
                                         unsigned short* Ath, unsigned short* Atl,
                                         int lane, int wn0) {
    const int r15 = lane & 15, q = lane >> 4;
#pragma unroll
    for (int mt = 0; mt < MT; mt++)
#pragma unroll
        for (int nt = 0; nt < 4; nt++) {
            int col = wn0 + nt * 16 + r15;
            float bb = b[col];
#pragma unroll
            for (int reg = 0; reg < 4; reg++) {
                int row = mt * 16 + q * 4 + reg;
                float z = av[mt][nt][reg] + bb;
                float h = softplus_fast(z);
                float ht = sigmoid_fast(z) * at[mt][nt][reg];
                unsigned short hi, lo;
                split2(h, hi, lo);
                Avh[row * AROW + col] = hi;
                Avl[row * AROW + col] = lo;
                split2(ht, hi, lo);
                Ath[row * AROW + col] = hi;
                Atl[row * AROW + col] = lo;
            }
        }
}

// layer3 activation + W4 dot; CH selects cheap vs exact softplus
template<int MT, bool CH>
__device__ __forceinline__ void l4_reduce(f32x4 acc[MT][4], const float* __restrict__ b3,
                                          const float* __restrict__ W4,
                                          float* partial, int lane, int wn0) {
    const int r15 = lane & 15, q = lane >> 4;
    float w4v[4], b3v[4];
#pragma unroll
    for (int nt = 0; nt < 4; nt++) {
        int col = wn0 + nt * 16 + r15;
        w4v[nt] = W4[col]; b3v[nt] = b3[col];
    }
#pragma unroll
    for (int mt = 0; mt < MT; mt++)
#pragma unroll
        for (int reg = 0; reg < 4; reg++) {
            float p = 0.f;
#pragma unroll
            for (int nt = 0; nt < 4; nt++) {
                float z = acc[mt][nt][reg] + b3v[nt];
                float h = CH ? softplus_cheap(z) : softplus_fast(z);
                p += h * w4v[nt];
            }
#pragma unroll
            for (int m = 1; m < 16; m <<= 1) p += __shfl_xor(p, m, 64);
            if (r15 == 0) partial[mt * 16 + q * 4 + reg] = p;
        }
}

template<int MT>
__device__ __forceinline__ void l4_reduce_dual(f32x4 av[MT][4], f32x4 at[MT][4],
                                               const float* __restrict__ b3, const float* __restrict__ W4,
                                               float* pv, float* pt, int lane, int wn0) {
    const int r15 = lane & 15, q = lane >> 4;
    float w4v[4], b3v[4];
#pragma unroll
    for (int nt = 0; nt < 4; nt++) {
        int col = wn0 + nt * 16 + r15;
        w4v[nt] = W4[col]; b3v[nt] = b3[col];
    }
#pragma unroll
    for (int mt = 0; mt < MT; mt++)
#pragma unroll
        for (int reg = 0; reg < 4; reg++) {
            float sv = 0.f, st = 0.f;
#pragma unroll
            for (int nt = 0; nt < 4; nt++) {
                float z = av[mt][nt][reg] + b3v[nt];
                sv += softplus_fast(z) * w4v[nt];
                st += sigmoid_fast(z) * at[mt][nt][reg] * w4v[nt];
            }
#pragma unroll
            for (int m = 1; m < 16; m <<= 1) {
                sv += __shfl_xor(sv, m, 64);
                st += __shfl_xor(st, m, 64);
            }
            if (r15 == 0) {
                pv[mt * 16 + q * 4 + reg] = sv;
                pt[mt * 16 + q * 4 + reg] = st;
            }
        }
}

// ---------------- coarse: block = (ray, half), 64 samples, MFMA layer1, inline flag ----------------
__global__ __launch_bounds__(256, 4)
void coarse_mfma(const float* __restrict__ rayinfo,
                 const unsigned short* __restrict__ B1,
                 const unsigned short* __restrict__ P2, const float* __restrict__ b2,
                 const unsigned short* __restrict__ P3, const float* __restrict__ b3,
                 const float* __restrict__ W4, const float* __restrict__ b4,
                 float* __restrict__ val_out, float* __restrict__ dprop_out,
                 int* __restrict__ fix_cnt, int* __restrict__ fix_list) {
    __shared__ __align__(16) unsigned short Ahi[64 * AROW];
    __shared__ __align__(16) unsigned short A1[64 * A1ROW];
    float* partial = (float*)A1;
    const int tid = threadIdx.x;
    const int lane = tid & 63, wave = tid >> 6;
    const int r = blockIdx.x >> 1, half = blockIdx.x & 1;

    if (tid < 64) {
        const float* ri = rayinfo + (size_t)r * 8;
        const int s = half * 64 + tid;
        float t = (float)s * (1.0f / 127.0f);
        float d = fmaf(t, ri[1], ri[0]);
        dprop_out[r * SSAMP + s] = d;
        float px = fmaf(d, ri[5], ri[2]);
        float py = fmaf(d, ri[6], ri[3]);
        float pz = fmaf(d, ri[7], ri[4]);
        unsigned short hx, lx, hy, ly, hz, lz;
        split2(px, hx, lx); split2(py, hy, ly); split2(pz, hz, lz);
        unsigned short* row = A1 + tid * A1ROW;
        row[0] = hx; row[1] = hy; row[2] = hz; row[3] = 0x3F80u;
        row[4] = lx; row[5] = ly; row[6] = lz; row[7] = 0x3F80u;
        row[8] = hx; row[9] = hy; row[10] = hz;
#pragma unroll
        for (int c = 11; c < 32; c++) row[c] = 0;
    }
    __syncthreads();
    f32x4 acc[4][4];
    gemm_l1<4>(A1, B1, acc, lane, wave * 4);
    epi_l1<4>(acc, Ahi, lane, wave * 64);
    __syncthreads();
    gemm_1t<4>(Ahi, P2, acc, lane, wave * 4);
    __syncthreads();
    epi_hidden_1t<4>(acc, b2, Ahi, lane, wave * 64);
    __syncthreads();
    gemm_1t<4>(Ahi, P3, acc, lane, wave * 4);
    l4_reduce<4, true>(acc, b3, W4, &partial[wave * 64], lane, wave * 64);
    __syncthreads();
    if (tid < 64) {
        float v = partial[tid] + partial[64 + tid] + partial[128 + tid] + partial[192 + tid] + b4[0];
        int idx = r * SSAMP + half * 64 + tid;
        val_out[idx] = v;
        if (fabsf(v) < FIXTHR) {
            int pos = atomicAdd(fix_cnt, 1);
            if (pos < FIXCAP) fix_list[pos] = idx;
        }
    }
}

// ---------------- fixup (32-sample 3-term MFMA batches, MFMA layer1, 4 blocks/CU) ----------------
__global__ __launch_bounds__(256, 4)
void fixup3_mfma(const int* __restrict__ counter, const int* __restrict__ list,
                 float* __restrict__ val, const float* __restrict__ dprop,
                 const float* __restrict__ ray0, const float* __restrict__ rdg,
                 const unsigned short* __restrict__ B1,
                 const unsigned short* __restrict__ P2, const float* __restrict__ b2,
                 const unsigned short* __restrict__ P3, const float* __restrict__ b3,
                 const float* __restrict__ W4, const float* __restrict__ b4) {
    __shared__ __align__(16) unsigned short Ahi[32 * AROW];
    __shared__ __align__(16) unsigned short Alo[32 * AROW];
    __shared__ __align__(16) unsigned short A1[32 * A1ROW];
    __shared__ float partial[4][32];
    __shared__ int bidxs[32];
    const int cnt = min(*counter, FIXCAP);
    const int base = blockIdx.x * 32;
    if (base >= cnt) return;
    const int tid = threadIdx.x;
    const int lane = tid & 63, wave = tid >> 6;
    if (tid < 32) {
        const int i = min(base + tid, cnt - 1);   // tail clamp: duplicates write same value
        const int bidx = list[i];
        bidxs[tid] = bidx;
        const int rr = bidx >> 7;                 // r-major: idx = r*SSAMP + s
        float d = dprop[bidx];
        float px = ray0[3 * rr] + d * rdg[3 * rr];
        float py = ray0[3 * rr + 1] + d * rdg[3 * rr + 1];
        float pz = ray0[3 * rr + 2] + d * rdg[3 * rr + 2];
        unsigned short hx, lx, hy, ly, hz, lz;
        split2(px, hx, lx); split2(py, hy, ly); split2(pz, hz, lz);
        unsigned short* row = A1 + tid * A1ROW;
        row[0] = hx; row[1] = hy; row[2] = hz; row[3] = 0x3F80u;
        row[4] = lx; row[5] = ly; row[6] = lz; row[7] = 0x3F80u;
        row[8] = hx; row[9] = hy; row[10] = hz;
#pragma unroll
        for (int c = 11; c < 32; c++) row[c] = 0;
    }
    __syncthreads();
    f32x4 acc[2][4];
    gemm_l1<2>(A1, B1, acc, lane, wave * 4);
    epi_l1_sp<2>(acc, Ahi, Alo, lane, wave * 64);
    __syncthreads();
    gemm_3t<2>(Ahi, Alo, P2, acc, lane, wave * 4);
    __syncthreads();
    epi_hidden_sp<2>(acc, b2, Ahi, Alo, lane, wave * 64);
    __syncthreads();
    gemm_3t<2>(Ahi, Alo, P3, acc, lane, wave * 4);
    l4_reduce<2, false>(acc, b3, W4, &partial[wave][0], lane, wave * 64);
    __syncthreads();
    if (tid < 32) {
        float v = partial[0][tid] + partial[1][tid] + partial[2][tid] + partial[3][tid] + b4[0];
        val[bidxs[tid]] = v;
    }
}

// ---------------- refine: scan + 8-iter secant + final dual, all in one (16 rays/block) ----------------
__global__ __launch_bounds__(256, 4)
void refine_mfma(const float* __restrict__ val, const float* __restrict__ dprop,
                 const float* __restrict__ ray0, const float* __restrict__ rdg,
                 const float* __restrict__ W1, const float* __restrict__ b1,
                 const unsigned short* __restrict__ P2, const float* __restrict__ b2,
                 const unsigned short* __restrict__ P3, const float* __restrict__ b3,
                 const float* __restrict__ W4, const float* __restrict__ b4,
                 float* __restrict__ out) {
    __shared__ __align__(16) unsigned short Avh[16 * AROW];
    __shared__ __align__(16) unsigned short Avl[16 * AROW];
    __shared__ __align__(16) unsigned short Ath[16 * AROW];
    __shared__ __align__(16) unsigned short Atl[16 * AROW];
    __shared__ float partial[4][16], ptan[4][16];
    __shared__ float dl[16], fl[16], dh[16], fh[16], dps[16];
    __shared__ int mks[16];
    unsigned short* Ahi = Avh;   // secant reuses plane 0
    const int tid = threadIdx.x;
    const int lane = tid & 63, wave = tid >> 6;
    const int r0 = blockIdx.x * 16;

    // ---- scan: wave w handles rays r0+w*4 .. +3 ----
    for (int i = 0; i < 4; i++) {
        const int r = r0 + wave * 4 + i;
        const float2 v = *(const float2*)(val + (size_t)r * SSAMP + lane * 2);
        const float2 dd = *(const float2*)(dprop + (size_t)r * SSAMP + lane * 2);
        float vnext = __shfl_down(v.x, 1, 64);
        const int s0 = lane * 2, s1 = s0 + 1;
        float pr0 = v.x * v.y;
        int sg0 = (pr0 > 0.f) ? 1 : ((pr0 < 0.f) ? -1 : 0);
        int k0 = (sg0 * (SSAMP - s0) + 129) * 256 + s0;
        int k1;
        if (lane == 63) {
            k1 = (1 + 129) * 256 + 127;          // appended cost[127] = 1
        } else {
            float pr1 = v.y * vnext;
            int sg1 = (pr1 > 0.f) ? 1 : ((pr1 < 0.f) ? -1 : 0);
            k1 = (sg1 * (SSAMP - s1) + 129) * 256 + s1;
        }
        int k = min(k0, k1);
#pragma unroll
        for (int m = 1; m < 64; m <<= 1) k = min(k, __shfl_xor(k, m, 64));
        int bidx = k & 255;
        int cmin = (k >> 8) - 129;
        int idxh = min(bidx + 1, SSAMP - 1);
        int ow = bidx >> 1, oh = idxh >> 1;
        float fa = __shfl(v.x, ow, 64), fb = __shfl(v.y, ow, 64);
        float da = __shfl(dd.x, ow, 64), db = __shfl(dd.y, ow, 64);
        float fa2 = __shfl(v.x, oh, 64), fb2 = __shfl(v.y, oh, 64);
        float da2 = __shfl(dd.x, oh, 64), db2 = __shfl(dd.y, oh, 64);
        float v0 = __shfl(v.x, 0, 64);
        if (lane == 0) {
            float f_low = (bidx & 1) ? fb : fa;
            float d_low = (bidx & 1) ? db : da;
            float f_high = (idxh & 1) ? fb2 : fa2;
            float d_high = (idxh & 1) ? db2 : da2;
            int sl = wave * 4 + i;
            mks[sl] = (cmin < 0) && (f_low < 0.f) && (v0 < 0.f);
            float den = f_high - f_low;
            if (fabsf(den) < 1e-12f) den = 1e-12f;
            dl[sl] = d_low; fl[sl] = f_low; dh[sl] = d_high; fh[sl] = f_high;
            dps[sl] = -f_low * (d_high - d_low) / den + d_low;
        }
    }
    __syncthreads();
    // ---- 8 secant iterations (1-term, cheap softplus) ----
    for (int it = 0; it < 8; it++) {
        {
            const int pt = tid >> 4, jb = (tid & 15) << 4;
            const int rr = r0 + pt;
            float d = dps[pt];
            float px = ray0[3 * rr] + d * rdg[3 * rr];
            float py = ray0[3 * rr + 1] + d * rdg[3 * rr + 1];
            float pz = ray0[3 * rr + 2] + d * rdg[3 * rr + 2];
            for (int j = jb; j < jb + 16; j += 4) {
                float4 wa = *(const float4*)(W1 + j);
                float4 wb = *(const float4*)(W1 + 256 + j);
                float4 wc = *(const float4*)(W1 + 512 + j);
                float4 bb = *(const float4*)(b1 + j);
                float z[4];
                z[0] = fmaf(px, wa.x, fmaf(py, wb.x, fmaf(pz, wc.x, bb.x)));
                z[1] = fmaf(px, wa.y, fmaf(py, wb.y, fmaf(pz, wc.y, bb.y)));
                z[2] = fmaf(px, wa.z, fmaf(py, wb.z, fmaf(pz, wc.z, bb.z)));
                z[3] = fmaf(px, wa.w, fmaf(py, wb.w, fmaf(pz, wc.w, bb.w)));
#pragma unroll
                for (int i = 0; i < 4; i++)
                    Ahi[pt * AROW + j + i] = f2bf(softplus_cheap(z[i]));
            }
        }
        __syncthreads();
        f32x4 acc[1][4];
        gemm_1t<1>(Ahi, P2, acc, lane, wave * 4);
        __syncthreads();
        epi_hidden_1t<1>(acc, b2, Ahi, lane, wave * 64);
        __syncthreads();
        gemm_1t<1>(Ahi, P3, acc, lane, wave * 4);
        l4_reduce<1, true>(acc, b3, W4, &partial[wave][0], lane, wave * 64);
        __syncthreads();
        if (tid < 16) {
            float fm = partial[0][tid] + partial[1][tid] + partial[2][tid] + partial[3][tid] + b4[0];
            float dpv = dps[tid];
            float dlv = dl[tid], flv = fl[tid], dhv = dh[tid], fhv = fh[tid];
            if (fm < 0.f) { dlv = dpv; flv = fm; } else { dhv = dpv; fhv = fm; }
            float den = fhv - flv;
            if (fabsf(den) < 1e-12f) den = 1e-12f;
            dps[tid] = -flv * (dhv - dlv) / den + dlv;
            dl[tid] = dlv; fl[tid] = flv; dh[tid] = dhv; fh[tid] = fhv;
        }
        __syncthreads();
    }
    // ---- final: dual-number 3-term eval + implicit correction ----
    {
        const int pt = tid >> 4, jb = (tid & 15) << 4;
        const int rr = r0 + pt;
        float d = dps[pt];
        float v0 = rdg[3 * rr], v1 = rdg[3 * rr + 1], v2 = rdg[3 * rr + 2];
        float px = ray0[3 * rr] + d * v0;
        float py = ray0[3 * rr + 1] + d * v1;
        float pz = ray0[3 * rr + 2] + d * v2;
        for (int j = jb; j < jb + 16; j += 4) {
            float4 wa = *(const float4*)(W1 + j);
            float4 wb = *(const float4*)(W1 + 256 + j);
            float4 wc = *(const float4*)(W1 + 512 + j);
            float4 bb = *(const float4*)(b1 + j);
            float z[4], zt[4];
            z[0] = fmaf(px, wa.x, fmaf(py, wb.x, fmaf(pz, wc.x, bb.x)));
            z[1] = fmaf(px, wa.y, fmaf(py, wb.y, fmaf(pz, wc.y, bb.y)));
            z[2] = fmaf(px, wa.z, fmaf(py, wb.z, fmaf(pz, wc.z, bb.z)));
            z[3] = fmaf(px, wa.w, fmaf(py, wb.w, fmaf(pz, wc.w, bb.w)));
            zt[0] = fmaf(v0, wa.x, fmaf(v1, wb.x, v2 * wc.x));
            zt[1] = fmaf(v0, wa.y, fmaf(v1, wb.y, v2 * wc.y));
            zt[2] = fmaf(v0, wa.z, fmaf(v1, wb.z, v2 * wc.z));
            zt[3] = fmaf(v0, wa.w, fmaf(v1, wb.w, v2 * wc.w));
#pragma unroll
            for (int i = 0; i < 4; i++) {
                float h = softplus_fast(z[i]);
                float ht = sigmoid_fast(z[i]) * zt[i];
                unsigned short hi, lo;
                split2(h, hi, lo);
                Avh[pt * AROW + j + i] = hi;
                Avl[pt * AROW + j + i] = lo;
                split2(ht, hi, lo);
                Ath[pt * AROW + j + i] = hi;
                Atl[pt * AROW + j + i] = lo;
            }
        }
    }
    __syncthreads();
    f32x4 av[1][4], at[1][4];
    gemm_dual<1>(Avh, Avl, Ath, Atl, P2, av, at, lane, wave * 4);
    __syncthreads();
    epi_dual<1>(av, at, b2, Avh, Avl, Ath, Atl, lane, wave * 64);
    __syncthreads();
    gemm_dual<1>(Avh, Avl, Ath, Atl, P3, av, at, lane, wave * 4);
    l4_reduce_dual<1>(av, at, b3, W4, &partial[wave][0], &ptan[wave][0], lane, wave * 64);
    __syncthreads();
    if (tid < 16) {
        float f = partial[0][tid] + partial[1][tid] + partial[2][tid] + partial[3][tid] + b4[0];
        float ft = ptan[0][tid] + ptan[1][tid] + ptan[2][tid] + ptan[3][tid];
        if (fabsf(ft) < 1e-6f) ft = (ft < 0.f) ? -1e-6f : 1e-6f;
        float dres = dps[tid] - f / ft;
        out[r0 + tid] = mks[tid] ? dres : 0.0f;
    }
}

extern "C" void kernel_launch(void* const* d_in, const int* in_sizes, int n_in,
                              void* d_out, int out_size, void* d_ws, size_t ws_size,
                              hipStream_t stream) {
    const float* ray0 = (const float*)d_in[0];
    const float* rdg  = (const float*)d_in[1];
    const float* W1 = (const float*)d_in[2];
    const float* b1 = (const float*)d_in[3];
    const float* W2 = (const float*)d_in[4];
    const float* b2 = (const float*)d_in[5];
    const float* W3 = (const float*)d_in[6];
    const float* b3 = (const float*)d_in[7];
    const float* W4 = (const float*)d_in[8];
    const float* b4 = (const float*)d_in[9];
    float* out = (float*)d_out;

    float* ws = (float*)d_ws;
    float* val    = ws;                                 // SSAMP*NRAY, r-major [r][s]
    float* dprop  = ws + (size_t)SSAMP * NRAY;          // r-major [r][s]
    unsigned short* P2 = (unsigned short*)(ws + (size_t)2 * SSAMP * NRAY);
    unsigned short* P3 = P2 + 131072;
    unsigned short* B1 = P3 + 131072;       // 8192 shorts
    float* rayinfo = (float*)(B1 + 8192);   // NRAY*8 floats
    int* fix_cnt  = (int*)(rayinfo + (size_t)NRAY * 8);
    int* fix_list = fix_cnt + 64;           // FIXCAP ints

    hipLaunchKernelGGL(prep_kernel, dim3(320), dim3(256), 0, stream,
                       W1, b1, W2, W3, ray0, rdg, P2, P3, B1, rayinfo, fix_cnt);
    hipLaunchKernelGGL(coarse_mfma, dim3(NRAY * 2), dim3(256), 0, stream,
                       rayinfo, B1, P2, b2, P3, b3, W4, b4, val, dprop, fix_cnt, fix_list);
    hipLaunchKernelGGL(fixup3_mfma, dim3(FIXCAP / 32), dim3(256), 0, stream,
                       fix_cnt, fix_list, val, dprop, ray0, rdg,
                       B1, P2, b2, P3, b3, W4, b4);
    hipLaunchKernelGGL(refine_mfma, dim3(NRAY / 16), dim3(256), 0, stream,
                       val, dprop, ray0, rdg, W1, b1, P2, b2, P3, b3, W4, b4, out);
}